// Round 16
// baseline (6486.956 us; speedup 1.0000x reference)
//
#include <hip/hip_runtime.h>
#include <hip/hip_bf16.h>
#include <cfloat>

// FPS matching the np reference bit-exactly (R7: PASS, absmax 0).
// FROZEN per-point arithmetic: dx=px-cx; y2=dy*dy; inner=fma(dx,dx,y2);
// d=fma(dz,dz,inner); nd=fminf(dist,d); winner=(max value, smallest index).
// R16: R13/R15 show ~92% per-active-CU VALUBusy -> VALU-issue bound. Pack
// points (k, k+16) into v2f so the frozen chain lowers to v_pk_*_f32
// (bit-exact per element, validated R12). Scan split into elem0-then-elem1
// passes to keep visit order = ascending point index (first-occurrence ties).
// R13 shape kept: 512 thr x 32 ppt, no pins (R15: pins hurt), u64-key reduce.

typedef float v2f __attribute__((ext_vector_type(2)));

#define FPS_THREADS 512

#define REP16(M) M(0) M(1) M(2) M(3) M(4) M(5) M(6) M(7) \
                 M(8) M(9) M(10) M(11) M(12) M(13) M(14) M(15)

__global__ __launch_bounds__(FPS_THREADS, 2)
void fps_kernel(const float* __restrict__ xyz, int* __restrict__ out_idx,
                int N, int S) {
#pragma clang fp contract(off)
  const int b = blockIdx.x;
  const int t = threadIdx.x;
  const float* xb = xyz + (size_t)b * N * 3;

  // pair (p, p+8192): p = k*512 + t, k = 0..15
#define DECLP(k) v2f px##k, py##k, pz##k, ds##k;
  REP16(DECLP)

#define LOADP(k) { int p = (k) * FPS_THREADS + t; int q = p + 8192;  \
    px##k = (v2f){xb[(size_t)p*3+0], xb[(size_t)q*3+0]};             \
    py##k = (v2f){xb[(size_t)p*3+1], xb[(size_t)q*3+1]};             \
    pz##k = (v2f){xb[(size_t)p*3+2], xb[(size_t)q*3+2]};             \
    ds##k = (v2f){FLT_MAX, FLT_MAX}; }
  REP16(LOADP)

  __shared__ unsigned long long s_k[2][FPS_THREADS / 64];

  const int wave = t >> 6;
  const int lane = t & 63;
  const unsigned invt = 0xFFFFFFFFu - (unsigned)t;
  int farthest = 0;

  for (int s = 0; s < S; ++s) {
    if (t == 0) out_idx[(size_t)b * S + s] = farthest;

    // centroid: block-uniform index -> scalar loads (L2-resident)
    int f = __builtin_amdgcn_readfirstlane(farthest);
    float cx = xb[(size_t)f * 3 + 0];
    float cy = xb[(size_t)f * 3 + 1];
    float cz = xb[(size_t)f * 3 + 2];
    v2f cx2 = (v2f){cx, cx}, cy2 = (v2f){cy, cy}, cz2 = (v2f){cz, cz};

    // pass 1: FROZEN chain, packed 2 points/op (bit-exact per element)
#define STEPP(k) {                                           \
    v2f dx = px##k - cx2;                                    \
    v2f dy = py##k - cy2;                                    \
    v2f dz = pz##k - cz2;                                    \
    v2f y2 = dy * dy;                                        \
    v2f inner = __builtin_elementwise_fma(dx, dx, y2);       \
    v2f dd = __builtin_elementwise_fma(dz, dz, inner);       \
    ds##k = __builtin_elementwise_min(ds##k, dd); }
    REP16(STEPP)

    // pass 2+3: scan in ascending point-index order (elem0 k=0..15 = points
    // [0,8192), then elem1 k=0..15 = points [8192,16384)) -> first-occurrence
    float bestv = -1.0f;
    int bestk = 0;   // 0..31; fits inline constant in v_cndmask
#define SCAN0(k) if (ds##k[0] > bestv) { bestv = ds##k[0]; bestk = (k); }
    REP16(SCAN0)
#define SCAN1(k) if (ds##k[1] > bestv) { bestv = ds##k[1]; bestk = (k) + 16; }
    REP16(SCAN1)

    // inverted original index: point = (bestk&15)*512 + t + (bestk>=16)*8192
    unsigned bestinv = invt - (unsigned)(((bestk & 15) * FPS_THREADS) +
                                         ((bestk >> 4) << 13));
    unsigned long long bestkkey =
        ((unsigned long long)__float_as_uint(bestv) << 32) |
        (unsigned long long)bestinv;

    // wave-level butterfly max over packed keys (dist >= 0 =>
    // u64 max == (max value, then smallest original index))
#pragma unroll
    for (int off = 32; off > 0; off >>= 1) {
      unsigned long long ok = __shfl_xor(bestkkey, off, 64);
      if (ok > bestkkey) bestkkey = ok;
    }

    // single barrier per step: parity double-buffer
    const int par = s & 1;
    if (lane == 0) s_k[par][wave] = bestkkey;
    __syncthreads();

    unsigned long long bk = s_k[par][0];
#pragma unroll
    for (int w = 1; w < FPS_THREADS / 64; ++w) {
      unsigned long long ok = s_k[par][w];
      if (ok > bk) bk = ok;
    }
    farthest = (int)(0xFFFFFFFFu - (unsigned)(bk & 0xFFFFFFFFu));
  }
}

// Gather: out = [ xyz[b][idx[b][s]][c] (B*S*3) , feat[b][idx[b][s]][:] (B*S*C) ]
__global__ void gather_kernel(const float* __restrict__ xyz,
                              const float* __restrict__ feat,
                              const int* __restrict__ idx,
                              float* __restrict__ out,
                              int B, int N, int S, int C) {
  const int c4pr = C >> 2;          // float4s per feat row
  const int nf4 = B * S * c4pr;     // total float4s of feat output
  int tid = blockIdx.x * blockDim.x + threadIdx.x;
  if (tid < nf4) {
    int c4 = tid % c4pr;
    int bs = tid / c4pr;
    int s = bs % S, b = bs / S;
    int p = idx[b * S + s];
    const float4* src = (const float4*)(feat + ((size_t)b * N + p) * C);
    float4* dst = (float4*)(out + (size_t)B * S * 3 + ((size_t)bs) * C);
    dst[c4] = src[c4];
  } else {
    int t2 = tid - nf4;
    int nxyz = B * S * 3;
    if (t2 < nxyz) {
      int c = t2 % 3;
      int bs = t2 / 3;
      int s = bs % S, b = bs / S;
      int p = idx[b * S + s];
      out[t2] = xyz[((size_t)b * N + p) * 3 + c];
    }
  }
}

extern "C" void kernel_launch(void* const* d_in, const int* in_sizes, int n_in,
                              void* d_out, int out_size, void* d_ws, size_t ws_size,
                              hipStream_t stream) {
  const float* xyz = (const float*)d_in[0];
  const float* feat = (const float*)d_in[1];
  float* out = (float*)d_out;

  const int B = 32;
  const int N = in_sizes[0] / (B * 3);        // 16384
  const int C = in_sizes[1] / (B * N);        // 128
  const int S = N / 4;                        // nsample = 0.25 * N = 4096

  int* d_idx = (int*)d_ws;  // B*S int32

  fps_kernel<<<B, FPS_THREADS, 0, stream>>>(xyz, d_idx, N, S);

  int total = B * S * (C >> 2) + B * S * 3;
  int blocks = (total + 255) / 256;
  gather_kernel<<<blocks, 256, 0, stream>>>(xyz, feat, d_idx, out, B, N, S, C);
}

// Round 17
// 6111.803 us; speedup vs baseline: 1.0614x; 1.0614x over previous
//
#include <hip/hip_runtime.h>
#include <hip/hip_bf16.h>
#include <cfloat>

// FPS matching the np reference bit-exactly (R7: PASS, absmax 0).
// FROZEN per-point arithmetic: dx=px-cx; y2=dy*dy; inner=fma(dx,dx,y2);
// d=fma(dz,dz,inner); nd=fminf(dist,d); winner=(max value, smallest index).
// R17: R13's VALU stream is mostly remat-load overhead on STRIDE-12 coords
// (12 lines/wave-load, 192KB/CU >> 32KB L1). R14 failed because z stayed
// stride-12. Fix: xy planes in LDS (128KB, ds_read_b64) + z bit-copied once
// to a DENSE per-batch plane in d_ws (stride-4 loads, 4 lines/wave-load,
// 64KB ~50% L1-resident). One variable vs R14: z contiguity.

#define FPS_THREADS 512

#define REP32(M) M(0) M(1) M(2) M(3) M(4) M(5) M(6) M(7) \
                 M(8) M(9) M(10) M(11) M(12) M(13) M(14) M(15) \
                 M(16) M(17) M(18) M(19) M(20) M(21) M(22) M(23) \
                 M(24) M(25) M(26) M(27) M(28) M(29) M(30) M(31)

__global__ __launch_bounds__(FPS_THREADS, 2)
void fps_kernel(const float* __restrict__ xyz, int* __restrict__ out_idx,
                float* __restrict__ zplane, int N, int S) {
#pragma clang fp contract(off)
  const int b = blockIdx.x;
  const int t = threadIdx.x;
  const float* xb = xyz + (size_t)b * N * 3;
  float* zb = zplane + (size_t)b * N;

  __shared__ float2 s_xy[16384];                 // 128 KB x,y planes
  __shared__ unsigned long long s_k[2][FPS_THREADS / 64];

#define DECLP(k) float pz##k, ds##k;
  REP32(DECLP)

  // prologue: stage xy -> LDS, z -> dense global plane (bit-exact copies)
#define LOADP(k) { int p = (k) * FPS_THREADS + t;               \
    float zx = xb[(size_t)p * 3 + 2];                           \
    s_xy[p] = make_float2(xb[(size_t)p * 3 + 0],                \
                          xb[(size_t)p * 3 + 1]);               \
    zb[p] = zx;                                                 \
    pz##k = zx;                                                 \
    ds##k = FLT_MAX; }
  REP32(LOADP)

  const int wave = t >> 6;
  const int lane = t & 63;
  const unsigned invt = 0xFFFFFFFFu - (unsigned)t;
  int farthest = 0;

  __syncthreads();  // s_xy + zb visible (same block reads only)

  for (int s = 0; s < S; ++s) {
    if (t == 0) out_idx[(size_t)b * S + s] = farthest;

    // centroid: uniform index -> LDS broadcast (x,y) + dense z-plane read
    int f = __builtin_amdgcn_readfirstlane(farthest);
    float cz = zb[f];
    float2 cxy = s_xy[f];
    float cx = cxy.x, cy = cxy.y;

    float bestv = -1.0f;
    int bestk = 0;   // k fits inline constant in v_cndmask

    // FROZEN reference arithmetic (LLVM DAG contraction form):
#define STEPP(k) {                                               \
    float2 xy = s_xy[(k) * FPS_THREADS + t];                     \
    float dx = xy.x - cx;                                        \
    float dy = xy.y - cy;                                        \
    float dz = pz##k - cz;                                       \
    float y2 = dy * dy;                                          \
    float inner = __builtin_fmaf(dx, dx, y2);                    \
    float dd = __builtin_fmaf(dz, dz, inner);                    \
    float nd = fminf(ds##k, dd);                                 \
    ds##k = nd;                                                  \
    if (nd > bestv) { bestv = nd; bestk = (k); } }
    REP32(STEPP)

    // pack once: (value bits << 32) | inverted original index
    unsigned bestinv = invt - (unsigned)(bestk * FPS_THREADS);
    unsigned long long bestkkey =
        ((unsigned long long)__float_as_uint(bestv) << 32) |
        (unsigned long long)bestinv;

    // wave butterfly max over u64 keys (dist >= 0 => key order ==
    // (value, then smaller original index))
#pragma unroll
    for (int off = 32; off > 0; off >>= 1) {
      unsigned long long ok = __shfl_xor(bestkkey, off, 64);
      if (ok > bestkkey) bestkkey = ok;
    }

    // single barrier per step: parity double-buffer
    const int par = s & 1;
    if (lane == 0) s_k[par][wave] = bestkkey;
    __syncthreads();

    unsigned long long bk = s_k[par][0];
#pragma unroll
    for (int w = 1; w < FPS_THREADS / 64; ++w) {
      unsigned long long ok = s_k[par][w];
      if (ok > bk) bk = ok;
    }
    farthest = (int)(0xFFFFFFFFu - (unsigned)(bk & 0xFFFFFFFFu));
  }
}

// Gather: out = [ xyz[b][idx[b][s]][c] (B*S*3) , feat[b][idx[b][s]][:] (B*S*C) ]
__global__ void gather_kernel(const float* __restrict__ xyz,
                              const float* __restrict__ feat,
                              const int* __restrict__ idx,
                              float* __restrict__ out,
                              int B, int N, int S, int C) {
  const int c4pr = C >> 2;          // float4s per feat row
  const int nf4 = B * S * c4pr;     // total float4s of feat output
  int tid = blockIdx.x * blockDim.x + threadIdx.x;
  if (tid < nf4) {
    int c4 = tid % c4pr;
    int bs = tid / c4pr;
    int s = bs % S, b = bs / S;
    int p = idx[b * S + s];
    const float4* src = (const float4*)(feat + ((size_t)b * N + p) * C);
    float4* dst = (float4*)(out + (size_t)B * S * 3 + ((size_t)bs) * C);
    dst[c4] = src[c4];
  } else {
    int t2 = tid - nf4;
    int nxyz = B * S * 3;
    if (t2 < nxyz) {
      int c = t2 % 3;
      int bs = t2 / 3;
      int s = bs % S, b = bs / S;
      int p = idx[b * S + s];
      out[t2] = xyz[((size_t)b * N + p) * 3 + c];
    }
  }
}

extern "C" void kernel_launch(void* const* d_in, const int* in_sizes, int n_in,
                              void* d_out, int out_size, void* d_ws, size_t ws_size,
                              hipStream_t stream) {
  const float* xyz = (const float*)d_in[0];
  const float* feat = (const float*)d_in[1];
  float* out = (float*)d_out;

  const int B = 32;
  const int N = in_sizes[0] / (B * 3);        // 16384
  const int C = in_sizes[1] / (B * N);        // 128
  const int S = N / 4;                        // nsample = 0.25 * N = 4096

  int* d_idx = (int*)d_ws;                    // B*S int32 = 512 KB
  float* d_z = (float*)((char*)d_ws + (size_t)B * S * sizeof(int));  // B*N f32 = 2 MB

  fps_kernel<<<B, FPS_THREADS, 0, stream>>>(xyz, d_idx, d_z, N, S);

  int total = B * S * (C >> 2) + B * S * 3;
  int blocks = (total + 255) / 256;
  gather_kernel<<<blocks, 256, 0, stream>>>(xyz, feat, d_idx, out, B, N, S, C);
}

// Round 18
// 5978.650 us; speedup vs baseline: 1.0850x; 1.0223x over previous
//
#include <hip/hip_runtime.h>
#include <hip/hip_bf16.h>
#include <cfloat>

// FPS matching the np reference bit-exactly (R7: PASS, absmax 0).
// FROZEN per-point arithmetic: dx=px-cx; y2=dy*dy; inner=fma(dx,dx,y2);
// d=fma(dz,dz,inner); nd=fminf(dist,d); winner=(max value, smallest index).
// R18 experiment: R13 re-reads 192KB/CU/step from L2; stride-12 wave-loads
// gather 12 lines each (TA cost 3x). Transpose once to dense {xy,z} planes
// -> 2 loads/pt at stride 8/4 (8+4 lines). Same bytes, 3x fewer TA line
// lookups. Discriminates TA-bound vs L2-bytes-bound before the bucket
// rewrite. Everything else is R13 verbatim.

#define FPS_THREADS 512

#define REP32(M) M(0) M(1) M(2) M(3) M(4) M(5) M(6) M(7) \
                 M(8) M(9) M(10) M(11) M(12) M(13) M(14) M(15) \
                 M(16) M(17) M(18) M(19) M(20) M(21) M(22) M(23) \
                 M(24) M(25) M(26) M(27) M(28) M(29) M(30) M(31)

__global__ __launch_bounds__(FPS_THREADS) void transpose_kernel(
    const float* __restrict__ xyz, float2* __restrict__ xyp,
    float* __restrict__ zp, int N) {
  const int b = blockIdx.x;
  const int t = threadIdx.x;
  const float* xb = xyz + (size_t)b * N * 3;
  float2* xyb = xyp + (size_t)b * N;
  float* zb = zp + (size_t)b * N;
#pragma unroll
  for (int k = 0; k < 32; ++k) {
    int p = k * FPS_THREADS + t;
    xyb[p] = make_float2(xb[(size_t)p * 3 + 0], xb[(size_t)p * 3 + 1]);
    zb[p] = xb[(size_t)p * 3 + 2];
  }
}

__global__ __launch_bounds__(FPS_THREADS, 2)
void fps_kernel(const float2* __restrict__ xyp, const float* __restrict__ zp,
                int* __restrict__ out_idx, int N, int S) {
#pragma clang fp contract(off)
  const int b = blockIdx.x;
  const int t = threadIdx.x;
  const float2* xyb = xyp + (size_t)b * N;
  const float* zb = zp + (size_t)b * N;

#define DECLP(k) float ds##k;
  REP32(DECLP)
#define INITP(k) ds##k = FLT_MAX;
  REP32(INITP)

  __shared__ unsigned long long s_k[2][FPS_THREADS / 64];

  const int wave = t >> 6;
  const int lane = t & 63;
  const unsigned invt = 0xFFFFFFFFu - (unsigned)t;
  int farthest = 0;

  for (int s = 0; s < S; ++s) {
    if (t == 0) out_idx[(size_t)b * S + s] = farthest;

    // centroid: block-uniform index -> scalar loads (L2-resident planes)
    int f = __builtin_amdgcn_readfirstlane(farthest);
    float2 cxy = xyb[f];
    float cz = zb[f];
    float cx = cxy.x, cy = cxy.y;

    float bestv = -1.0f;
    int bestk = 0;   // k fits inline constant in v_cndmask

    // FROZEN reference arithmetic (LLVM DAG contraction form):
#define STEPP(k) {                                               \
    int p = (k) * FPS_THREADS + t;                               \
    float2 xy = xyb[p];                                          \
    float dz = zb[p] - cz;                                       \
    float dx = xy.x - cx;                                        \
    float dy = xy.y - cy;                                        \
    float y2 = dy * dy;                                          \
    float inner = __builtin_fmaf(dx, dx, y2);                    \
    float dd = __builtin_fmaf(dz, dz, inner);                    \
    float nd = fminf(ds##k, dd);                                 \
    ds##k = nd;                                                  \
    if (nd > bestv) { bestv = nd; bestk = (k); } }
    REP32(STEPP)

    // inverted index once per step: inv = (0xFFFFFFFF - t) - k*512
    unsigned bestinv = invt - (unsigned)(bestk * FPS_THREADS);
    unsigned long long bestkkey =
        ((unsigned long long)__float_as_uint(bestv) << 32) |
        (unsigned long long)bestinv;

    // wave-level butterfly max over packed keys (dist >= 0 =>
    // u64 max == (max value, then smallest original index))
#pragma unroll
    for (int off = 32; off > 0; off >>= 1) {
      unsigned long long ok = __shfl_xor(bestkkey, off, 64);
      if (ok > bestkkey) bestkkey = ok;
    }

    // single barrier per step: parity double-buffer
    const int par = s & 1;
    if (lane == 0) s_k[par][wave] = bestkkey;
    __syncthreads();

    unsigned long long bk = s_k[par][0];
#pragma unroll
    for (int w = 1; w < FPS_THREADS / 64; ++w) {
      unsigned long long ok = s_k[par][w];
      if (ok > bk) bk = ok;
    }
    farthest = (int)(0xFFFFFFFFu - (unsigned)(bk & 0xFFFFFFFFu));
  }
}

// Gather: out = [ xyz[b][idx[b][s]][c] (B*S*3) , feat[b][idx[b][s]][:] (B*S*C) ]
__global__ void gather_kernel(const float* __restrict__ xyz,
                              const float* __restrict__ feat,
                              const int* __restrict__ idx,
                              float* __restrict__ out,
                              int B, int N, int S, int C) {
  const int c4pr = C >> 2;          // float4s per feat row
  const int nf4 = B * S * c4pr;     // total float4s of feat output
  int tid = blockIdx.x * blockDim.x + threadIdx.x;
  if (tid < nf4) {
    int c4 = tid % c4pr;
    int bs = tid / c4pr;
    int s = bs % S, b = bs / S;
    int p = idx[b * S + s];
    const float4* src = (const float4*)(feat + ((size_t)b * N + p) * C);
    float4* dst = (float4*)(out + (size_t)B * S * 3 + ((size_t)bs) * C);
    dst[c4] = src[c4];
  } else {
    int t2 = tid - nf4;
    int nxyz = B * S * 3;
    if (t2 < nxyz) {
      int c = t2 % 3;
      int bs = t2 / 3;
      int s = bs % S, b = bs / S;
      int p = idx[b * S + s];
      out[t2] = xyz[((size_t)b * N + p) * 3 + c];
    }
  }
}

extern "C" void kernel_launch(void* const* d_in, const int* in_sizes, int n_in,
                              void* d_out, int out_size, void* d_ws, size_t ws_size,
                              hipStream_t stream) {
  const float* xyz = (const float*)d_in[0];
  const float* feat = (const float*)d_in[1];
  float* out = (float*)d_out;

  const int B = 32;
  const int N = in_sizes[0] / (B * 3);        // 16384
  const int C = in_sizes[1] / (B * N);        // 128
  const int S = N / 4;                        // nsample = 0.25 * N = 4096

  // d_ws layout: idx (B*S*4 = 512KB) | xy planes (B*N*8 = 4MB) | z (B*N*4 = 2MB)
  int* d_idx = (int*)d_ws;
  float2* d_xy = (float2*)((char*)d_ws + (size_t)B * S * sizeof(int));
  float* d_z = (float*)((char*)d_xy + (size_t)B * N * sizeof(float2));

  transpose_kernel<<<B, FPS_THREADS, 0, stream>>>(xyz, d_xy, d_z, N);
  fps_kernel<<<B, FPS_THREADS, 0, stream>>>(d_xy, d_z, d_idx, N, S);

  int total = B * S * (C >> 2) + B * S * 3;
  int blocks = (total + 255) / 256;
  gather_kernel<<<blocks, 256, 0, stream>>>(xyz, feat, d_idx, out, B, N, S, C);
}

// Round 19
// 5697.123 us; speedup vs baseline: 1.1386x; 1.0494x over previous
//
#include <hip/hip_runtime.h>
#include <hip/hip_bf16.h>
#include <cfloat>

// FPS matching the np reference bit-exactly (R7: PASS, absmax 0).
// FROZEN per-point arithmetic: dx=px-cx; y2=dy*dy; inner=fma(dx,dx,y2);
// d=fma(dz,dz,inner); nd=fminf(dist,d); winner=(max value, smallest index).
// R19: R18 proved full-scan is L2-BYTES-bound (192KB/step / 56B/cy = 3430cy
// = measured). Split across pipes: xy in LDS via ds_read_b128 (85B/cy, the
// only efficient LDS width per m134) + z dense global (VMEM). Pipes overlap.
// DPP (VALU-pipe) wave reduction replaces ds_bpermute shfl butterfly
// (~400-700cy serial LDS latency -> ~60cy).

#define FPS_THREADS 512

#define REP16(M) M(0) M(1) M(2) M(3) M(4) M(5) M(6) M(7) \
                 M(8) M(9) M(10) M(11) M(12) M(13) M(14) M(15)

// DPP helpers: ctrl as template param -> guaranteed constant fold.
// Sequence xor1,xor2,half_mirror,mirror,bcast15,bcast31 leaves the
// 64-lane max in lane 63.
template <int CTRL>
__device__ __forceinline__ float dpp_maxf(float v) {
  int iv = __float_as_int(v);
  int sh = __builtin_amdgcn_update_dpp(iv, iv, CTRL, 0xF, 0xF, false);
  return fmaxf(v, __int_as_float(sh));
}
template <int CTRL>
__device__ __forceinline__ unsigned dpp_maxu(unsigned v) {
  int sh = __builtin_amdgcn_update_dpp((int)v, (int)v, CTRL, 0xF, 0xF, false);
  return ((unsigned)sh > v) ? (unsigned)sh : v;
}
__device__ __forceinline__ float wave_maxf(float v) {
  v = dpp_maxf<0xB1>(v);   // quad_perm xor1
  v = dpp_maxf<0x4E>(v);   // quad_perm xor2
  v = dpp_maxf<0x141>(v);  // row_half_mirror (xor4)
  v = dpp_maxf<0x140>(v);  // row_mirror (xor8)
  v = dpp_maxf<0x142>(v);  // row_bcast15
  v = dpp_maxf<0x143>(v);  // row_bcast31 -> lane63 has max
  return __int_as_float(__builtin_amdgcn_readlane(__float_as_int(v), 63));
}
__device__ __forceinline__ unsigned wave_maxu(unsigned v) {
  v = dpp_maxu<0xB1>(v);
  v = dpp_maxu<0x4E>(v);
  v = dpp_maxu<0x141>(v);
  v = dpp_maxu<0x140>(v);
  v = dpp_maxu<0x142>(v);
  v = dpp_maxu<0x143>(v);
  return (unsigned)__builtin_amdgcn_readlane((int)v, 63);
}

__global__ __launch_bounds__(FPS_THREADS) void transpose_kernel(
    const float* __restrict__ xyz, float2* __restrict__ xyp,
    float* __restrict__ zp, int N) {
  const int b = blockIdx.x;
  const int t = threadIdx.x;
  const float* xb = xyz + (size_t)b * N * 3;
  float2* xyb = xyp + (size_t)b * N;
  float* zb = zp + (size_t)b * N;
#pragma unroll
  for (int k = 0; k < 32; ++k) {
    int p = k * FPS_THREADS + t;
    xyb[p] = make_float2(xb[(size_t)p * 3 + 0], xb[(size_t)p * 3 + 1]);
    zb[p] = xb[(size_t)p * 3 + 2];
  }
}

__global__ __launch_bounds__(FPS_THREADS, 2)
void fps_kernel(const float2* __restrict__ xyp, const float* __restrict__ zp,
                int* __restrict__ out_idx, int N, int S) {
#pragma clang fp contract(off)
  const int b = blockIdx.x;
  const int t = threadIdx.x;
  const float4* xyb4 = (const float4*)(xyp + (size_t)b * N);  // [x0 y0 x1 y1]
  const float2* zb2 = (const float2*)(zp + (size_t)b * N);    // [z0 z1]
  const float* zb = zp + (size_t)b * N;

  __shared__ float4 s_xy4[8192];   // 128 KB: entry e <-> points 2e, 2e+1
  __shared__ unsigned long long s_k[2][FPS_THREADS / 64];

  // dist for points p0 = k*1024 + 2t, p1 = p0+1, k = 0..15
#define DECLP(k) float dsA##k, dsB##k;
  REP16(DECLP)

  // prologue: copy dense xy plane into LDS (bit-exact), init dist
#define LOADP(k) { int e = (k) * FPS_THREADS + t;  \
    s_xy4[e] = xyb4[e];                            \
    dsA##k = FLT_MAX; dsB##k = FLT_MAX; }
  REP16(LOADP)

  const int wave = t >> 6;
  const int lane = t & 63;
  const unsigned invt2 = 0xFFFFFFFFu - (unsigned)(2 * t);
  int farthest = 0;

  __syncthreads();  // s_xy4 visible

  for (int s = 0; s < S; ++s) {
    if (t == 0) out_idx[(size_t)b * S + s] = farthest;

    // centroid: uniform index f -> LDS entry (f>>10)*512 + ((f&1023)>>1),
    // element j = f&1 ; z from dense plane (scalar L2 load, consumed last)
    int f = __builtin_amdgcn_readfirstlane(farthest);
    float cz = zb[f];
    float4 cq = s_xy4[(f >> 10) * FPS_THREADS + ((f & 1023) >> 1)];
    int j = f & 1;
    float cx = j ? cq.z : cq.x;
    float cy = j ? cq.w : cq.y;

    float bestv = -1.0f;
    int bestk = 0, bestj = 0;   // both fit inline constants in v_cndmask

    // FROZEN reference arithmetic; scan ascending (p0 then p1, k ascending)
#define STEPP(k) {                                               \
    int e = (k) * FPS_THREADS + t;                               \
    float4 q = s_xy4[e];                                         \
    float2 z2 = zb2[e];                                          \
    { float dx = q.x - cx, dy = q.y - cy, dz = z2.x - cz;        \
      float y2 = dy * dy;                                        \
      float inner = __builtin_fmaf(dx, dx, y2);                  \
      float dd = __builtin_fmaf(dz, dz, inner);                  \
      float nd = fminf(dsA##k, dd);                              \
      dsA##k = nd;                                               \
      if (nd > bestv) { bestv = nd; bestk = (k); bestj = 0; } }  \
    { float dx = q.z - cx, dy = q.w - cy, dz = z2.y - cz;        \
      float y2 = dy * dy;                                        \
      float inner = __builtin_fmaf(dx, dx, y2);                  \
      float dd = __builtin_fmaf(dz, dz, inner);                  \
      float nd = fminf(dsB##k, dd);                              \
      dsB##k = nd;                                               \
      if (nd > bestv) { bestv = nd; bestk = (k); bestj = 1; } } }
    REP16(STEPP)

    // inv original index: orig = bestk*1024 + 2t + bestj
    unsigned bestinv = invt2 - (unsigned)((bestk << 10) + bestj);

    // wave reduce via DPP (VALU pipe): max value, then max inv among ties
    float wmax = wave_maxf(bestv);
    unsigned cand = (bestv == wmax) ? bestinv : 0u;
    unsigned winv = wave_maxu(cand);

    // single barrier per step: parity double-buffer
    const int par = s & 1;
    if (lane == 0)
      s_k[par][wave] = ((unsigned long long)__float_as_uint(wmax) << 32) |
                       (unsigned long long)winv;
    __syncthreads();

    unsigned long long bk = s_k[par][0];
#pragma unroll
    for (int w = 1; w < FPS_THREADS / 64; ++w) {
      unsigned long long ok = s_k[par][w];
      if (ok > bk) bk = ok;
    }
    farthest = (int)(0xFFFFFFFFu - (unsigned)(bk & 0xFFFFFFFFu));
  }
}

// Gather: out = [ xyz[b][idx[b][s]][c] (B*S*3) , feat[b][idx[b][s]][:] (B*S*C) ]
__global__ void gather_kernel(const float* __restrict__ xyz,
                              const float* __restrict__ feat,
                              const int* __restrict__ idx,
                              float* __restrict__ out,
                              int B, int N, int S, int C) {
  const int c4pr = C >> 2;          // float4s per feat row
  const int nf4 = B * S * c4pr;     // total float4s of feat output
  int tid = blockIdx.x * blockDim.x + threadIdx.x;
  if (tid < nf4) {
    int c4 = tid % c4pr;
    int bs = tid / c4pr;
    int s = bs % S, b = bs / S;
    int p = idx[b * S + s];
    const float4* src = (const float4*)(feat + ((size_t)b * N + p) * C);
    float4* dst = (float4*)(out + (size_t)B * S * 3 + ((size_t)bs) * C);
    dst[c4] = src[c4];
  } else {
    int t2 = tid - nf4;
    int nxyz = B * S * 3;
    if (t2 < nxyz) {
      int c = t2 % 3;
      int bs = t2 / 3;
      int s = bs % S, b = bs / S;
      int p = idx[b * S + s];
      out[t2] = xyz[((size_t)b * N + p) * 3 + c];
    }
  }
}

extern "C" void kernel_launch(void* const* d_in, const int* in_sizes, int n_in,
                              void* d_out, int out_size, void* d_ws, size_t ws_size,
                              hipStream_t stream) {
  const float* xyz = (const float*)d_in[0];
  const float* feat = (const float*)d_in[1];
  float* out = (float*)d_out;

  const int B = 32;
  const int N = in_sizes[0] / (B * 3);        // 16384
  const int C = in_sizes[1] / (B * N);        // 128
  const int S = N / 4;                        // nsample = 0.25 * N = 4096

  // d_ws layout: idx (512KB) | xy planes (4MB, 16B-aligned) | z (2MB)
  int* d_idx = (int*)d_ws;
  float2* d_xy = (float2*)((char*)d_ws + (size_t)B * S * sizeof(int));
  float* d_z = (float*)((char*)d_xy + (size_t)B * N * sizeof(float2));

  transpose_kernel<<<B, FPS_THREADS, 0, stream>>>(xyz, d_xy, d_z, N);
  fps_kernel<<<B, FPS_THREADS, 0, stream>>>(d_xy, d_z, d_idx, N, S);

  int total = B * S * (C >> 2) + B * S * 3;
  int blocks = (total + 255) / 256;
  gather_kernel<<<blocks, 256, 0, stream>>>(xyz, feat, d_idx, out, B, N, S, C);
}